// Round 14
// baseline (146.937 us; speedup 1.0000x reference)
//
#include <hip/hip_runtime.h>
#include <stdint.h>

// VectorQuantize: x (8,256,32,32) f32, embed_w (4096,256) f32
// M = 8192 rows, K = 4096 codes, d = 256
// out (floats): [0,2097152) x_q (b,c,h,w); [2097152] loss; [2097153,2105345) embed_ind
//
// Round 14: R13 (146.8us, best) with one zero-risk prep simplification: the
// x-split unit now loads directly from global (lane-consecutive n => already
// coalesced) instead of round-tripping through LDS with 2 barriers. Identical
// values, identical stores, identical numerics. Gemm/out byte-identical to R13.
// Structural ceilings (measured): gemm 67us = m97 plateau; 3 launches minimal.

typedef _Float16 f16;
typedef f16 half8 __attribute__((ext_vector_type(8)));
typedef float f32x4 __attribute__((ext_vector_type(4)));

__device__ __forceinline__ unsigned int sortable_f32(float v) {
    unsigned int u = __float_as_uint(v);
    return (u & 0x80000000u) ? ~u : (u | 0x80000000u);
}

__device__ __forceinline__ void gload_lds16(const void* g, void* l) {
    __builtin_amdgcn_global_load_lds(
        (const __attribute__((address_space(1))) unsigned int*)g,
        (__attribute__((address_space(3))) unsigned int*)l, 16, 0, 0);
}

// ================= K1: all prep, race-free unit partition (grid 1152) =================
__global__ void vq_prep(const float* __restrict__ x, const float* __restrict__ ew,
                        float* __restrict__ e2, float* __restrict__ negx2,
                        unsigned long long* __restrict__ cand,
                        f16* __restrict__ ehi, f16* __restrict__ elo,
                        f16* __restrict__ xhi, f16* __restrict__ xlo,
                        float* __restrict__ loss_cell) {
    const int u = blockIdx.x, tid = threadIdx.x;
    if (u < 512) {
        // e-split (x 2^12, exact) into swizzled planes
        const int t = u * 256 + tid;            // 131072 = 4096 k * 32 groups
        const int k = t >> 5, g32 = t & 31;
        const float4 v0 = *(const float4*)(ew + k * 256 + g32 * 8);
        const float4 v1 = *(const float4*)(ew + k * 256 + g32 * 8 + 4);
        const float vf[8] = {v0.x, v0.y, v0.z, v0.w, v1.x, v1.y, v1.z, v1.w};
        half8 h1, h2;
#pragma unroll
        for (int j = 0; j < 8; ++j) {
            const float v = vf[j] * 4096.0f;    // exact (power of 2)
            const f16 a = (f16)v;
            const f16 b = (f16)(v - (float)a);  // exact in fp32
            h1[j] = a; h2[j] = b;
        }
        const int kt = k >> 7, kk = k & 127, ci = g32 >> 2, g = g32 & 3;
        const long off = ((long)((kt * 8 + ci) * 128 + kk)) * 32 + ((g ^ (kk & 3)) * 8);
        *(half8*)(ehi + off) = h1;
        *(half8*)(elo + off) = h2;
    } else if (u < 544) {
        // e2: same float4 loop as all passing rounds, spread over 32 blocks
        if (tid < 128) {
            const int k = (u - 512) * 128 + tid;
            const float4* row = (const float4*)(ew + k * 256);
            float s = 0.0f;
#pragma unroll 8
            for (int i = 0; i < 64; ++i) {
                float4 v = row[i];
                s += v.x * v.x + v.y * v.y + v.z * v.z + v.w * v.w;
            }
            e2[k] = s;
        }
    } else if (u < 576) {
        const int z = (u - 544) * 256 + tid;    // 8192
        cand[z] = 0ull;
        if (z == 0) *loss_cell = 0.0f;
    } else if (u < 640) {
        // negx2: one row per thread, IDENTICAL per-row c order (bit-exact invariant)
        if (tid < 128) {
            const int r = (u - 576) * 128 + tid;
            const int b = r >> 10, n = r & 1023;
            const float* px = x + b * 262144 + n;
            float s = 0.0f;
#pragma unroll 16
            for (int c = 0; c < 256; ++c) {
                float v = px[c << 10];
                s += v * v;
            }
            negx2[r] = -s;
        }
    } else {
        // x-split: transpose (b,c,n)->(m,d) + fp16 split into swizzled planes.
        // Direct global loads: lanes span consecutive n => fully coalesced; no LDS.
        const int unit = u - 640;               // 0..511
        const int ci = unit & 7, mt = unit >> 3;
        const int b = mt >> 3, n0 = (mt & 7) * 128, c0 = ci * 32;
#pragma unroll
        for (int it = 0; it < 2; ++it) {
            const int idx = tid + it * 256;
            const int mm = idx & 127, g = idx >> 7;
            const float* px = x + (size_t)b * 262144 + (size_t)(c0 + g * 8) * 1024 + n0 + mm;
            half8 h1, h2;
#pragma unroll
            for (int j = 0; j < 8; ++j) {
                const float v = px[(size_t)j << 10];
                const f16 a = (f16)v;
                const f16 bb = (f16)(v - (float)a);
                h1[j] = a; h2[j] = bb;
            }
            const long off = ((long)((mt * 8 + ci) * 128 + mm)) * 32 + ((g ^ (mm & 3)) * 8);
            *(half8*)(xhi + off) = h1;
            *(half8*)(xlo + off) = h2;
        }
    }
}

// ================= K2: gemm — R8/R11/R13's proven version, byte-for-byte =================
__launch_bounds__(256, 2)
__global__ void vq_gemm(const f16* __restrict__ xhi, const f16* __restrict__ xlo,
                        const f16* __restrict__ ehi, const f16* __restrict__ elo,
                        const float* __restrict__ e2, const float* __restrict__ negx2,
                        unsigned long long* __restrict__ cand) {
    __shared__ __align__(16) f16 lds[8192];   // 16 KB: xhi | xlo, 4096 halves each
    const int tid = threadIdx.x;
    const int kt = blockIdx.x, mt = blockIdx.y;
    const int lane = tid & 63, wave = tid >> 6;
    const int wm = wave >> 1, wk = wave & 1;
    const int col = lane & 15, quad = lane >> 4;

    f32x4 acc[4][4] = {};

    const f16* gx[2] = { xhi + (size_t)(mt * 8) * 4096, xlo + (size_t)(mt * 8) * 4096 };
    const f16* geh = ehi + (size_t)(kt * 8) * 4096;
    const f16* gel = elo + (size_t)(kt * 8) * 4096;

    int aoff[4], boff[4];
#pragma unroll
    for (int i = 0; i < 4; ++i) {
        const int m = wm * 64 + i * 16 + col;
        aoff[i] = m * 32 + ((quad ^ (m & 3)) * 8);
        const int k = wk * 64 + i * 16 + col;
        boff[i] = k * 32 + ((quad ^ (k & 3)) * 8);   // same XOR layout baked into planes
    }

    for (int ci = 0; ci < 8; ++ci) {
        __syncthreads();
        const int go = ci * 4096 + tid * 8;             // halves
        char* lb = (char*)lds + wave * 1024;            // wave-uniform dst base
#pragma unroll
        for (int p = 0; p < 2; ++p) {
            gload_lds16(gx[p] + go,        lb + p * 8192);
            gload_lds16(gx[p] + go + 2048, lb + p * 8192 + 4096);
        }
        // B fragments: direct global loads (L2-resident e-planes, fully coalesced
        // via the XOR swizzle baked into the plane layout)
        half8 bhi4[4], blo4[4];
#pragma unroll
        for (int j = 0; j < 4; ++j) {
            bhi4[j] = *(const half8*)(geh + ci * 4096 + boff[j]);
            blo4[j] = *(const half8*)(gel + ci * 4096 + boff[j]);
        }
        __syncthreads();

        half8 ahi4[4], alo4[4];
#pragma unroll
        for (int i = 0; i < 4; ++i) {
            ahi4[i] = *(const half8*)&lds[aoff[i]];
            alo4[i] = *(const half8*)&lds[4096 + aoff[i]];
        }
#pragma unroll
        for (int i = 0; i < 4; ++i)
#pragma unroll
            for (int j = 0; j < 4; ++j) {
                acc[i][j] = __builtin_amdgcn_mfma_f32_16x16x32_f16(ahi4[i], bhi4[j], acc[i][j], 0, 0, 0);
                acc[i][j] = __builtin_amdgcn_mfma_f32_16x16x32_f16(ahi4[i], blo4[j], acc[i][j], 0, 0, 0);
                acc[i][j] = __builtin_amdgcn_mfma_f32_16x16x32_f16(alo4[i], bhi4[j], acc[i][j], 0, 0, 0);
            }
    }

    // epilogue: C layout col=lane&15, row=quad*4+reg
    const int m0 = mt * 128 + wm * 64, k0 = kt * 128 + wk * 64;
#pragma unroll
    for (int i = 0; i < 4; ++i)
#pragma unroll
        for (int r = 0; r < 4; ++r) {
            const float A = negx2[m0 + i * 16 + quad * 4 + r];
            unsigned long long bk = 0ull;
#pragma unroll
            for (int j = 0; j < 4; ++j) {
                const int k = k0 + j * 16 + col;
                const float t1 = A - e2[k];                        // rounding 1
                const float dist = t1 + acc[i][j][r] * 0x1p-11f;   // exact scale; rounding 2
                const unsigned long long key =
                    ((unsigned long long)sortable_f32(dist) << 32)
                    | (unsigned long long)(unsigned int)(4095 - k);
                if (key > bk) bk = key;
            }
#pragma unroll
            for (int mask = 1; mask <= 8; mask <<= 1) {
                const unsigned long long o = __shfl_xor(bk, mask, 64);
                if (o > bk) bk = o;
            }
            if (col == i * 4 + r)
                atomicMax(&cand[m0 + i * 16 + quad * 4 + r], bk);
        }
}

// ================= K3: gather + transposed x_q store + ind + loss-from-cand =================
__global__ void vq_out(const float* __restrict__ ew,
                       const unsigned long long* __restrict__ cand,
                       float* __restrict__ out) {
    __shared__ int sidx[64];
    const int tid = threadIdx.x;
    const int r0 = blockIdx.x * 64;
    const int cq0 = blockIdx.y * 64;
    const int b = r0 >> 10, n0 = r0 & 1023;

    if (tid < 64) {
        const int r = r0 + tid;
        const unsigned long long bk = cand[r];
        const int idx = 4095 - (int)(unsigned int)(bk & 0xFFFFFFFFull);
        sidx[tid] = idx;
        if (cq0 == 0) {
            out[2097153 + r] = (float)idx;
            // decode dist (always negative here): -dist == ||x-e||^2 for this row
            const unsigned int s = (unsigned int)(bk >> 32);
            const unsigned int ubits = (s & 0x80000000u) ? (s & 0x7FFFFFFFu) : ~s;
            float nd = -__uint_as_float(ubits);
#pragma unroll
            for (int m = 1; m <= 32; m <<= 1) nd += __shfl_xor(nd, m, 64);
            if (tid == 0)
                atomicAdd(&out[2097152], 1.25f * (nd / 2097152.0f));
        }
    }
    __syncthreads();

    const int nn = tid & 63, cq = tid >> 6;
    const float* erow = ew + (size_t)sidx[nn] * 256 + cq0;
    float* ocol = out + (size_t)b * 262144 + ((size_t)cq0 << 10) + n0 + nn;
#pragma unroll
    for (int cb = 0; cb < 16; ++cb) {
        const int c = cb * 4 + cq;
        ocol[(size_t)c << 10] = erow[c];    // stores coalesced along nn
    }
}

extern "C" void kernel_launch(void* const* d_in, const int* in_sizes, int n_in,
                              void* d_out, int out_size, void* d_ws, size_t ws_size,
                              hipStream_t stream) {
    const float* x  = (const float*)d_in[0];
    const float* ew = (const float*)d_in[1];
    float* out = (float*)d_out;

    float* e2 = (float*)d_ws;                                              // 16 KB
    float* negx2 = e2 + 4096;                                              // 32 KB
    unsigned long long* cand = (unsigned long long*)((char*)d_ws + 49152); // 64 KB
    f16* ehi = (f16*)((char*)d_ws + 114688);                               // 2 MB (4K-aligned)
    f16* elo = (f16*)((char*)d_ws + 114688 + 2097152);                     // 2 MB
    f16* xhi = (f16*)out;                                                  // x_q region scratch
    f16* xlo = (f16*)(out + 1048576);

    vq_prep<<<1152, 256, 0, stream>>>(x, ew, e2, negx2, cand,
                                      ehi, elo, xhi, xlo, out + 2097152);
    vq_gemm<<<dim3(32, 64), 256, 0, stream>>>(xhi, xlo, ehi, elo, e2, negx2, cand);
    vq_out<<<dim3(128, 4), 256, 0, stream>>>(ew, cand, out);
}